// Round 2
// baseline (1891.797 us; speedup 1.0000x reference)
//
#include <hip/hip_runtime.h>

// ---------------- problem constants ----------------
#define B_  128
#define S_  200
#define F_  32
#define D_  512
#define NH_ 4
#define DH_ 128
#define KK_ 4
#define NB_ 2
#define UP_ 704
#define FD_ 7
#define M_  (B_*S_)   // 25600 rows

typedef unsigned short u16;
typedef __attribute__((ext_vector_type(8))) short  s16x8;
typedef __attribute__((ext_vector_type(4))) float  f32x4;

__device__ __forceinline__ u16 f2bf(float f){
  unsigned x = __builtin_bit_cast(unsigned, f);
  return (u16)((x + 0x7fffu + ((x>>16)&1u)) >> 16);   // RNE
}
__device__ __forceinline__ float bf2f(u16 u){
  return __builtin_bit_cast(float, (unsigned)u << 16);
}
__device__ __forceinline__ f32x4 mfma16(s16x8 a, s16x8 b, f32x4 c){
  return __builtin_amdgcn_mfma_f32_16x16x32_bf16(a, b, c, 0, 0, 0);
}

// ---------------- tiny utility kernels ----------------
__global__ void k_cast(const float* __restrict__ in, u16* __restrict__ out, int n){
  int i = blockIdx.x*256 + threadIdx.x;
  if (i < n) out[i] = f2bf(in[i]);
}
__global__ void k_zero(float* __restrict__ p, int n){
  int i = blockIdx.x*256 + threadIdx.x;
  if (i < n) p[i] = 0.f;
}
__global__ void k_sentinel(float* __restrict__ out, int n){
  int i = blockIdx.x*256 + threadIdx.x;
  if (i < n) out[i] = -12345.0f;
}

// ---------------- input projection: h = x @ w_in + b_in ----------------
__global__ __launch_bounds__(256) void k_inproj(const float* __restrict__ x,
    const float* __restrict__ w, const float* __restrict__ bias, float* __restrict__ h)
{
  __shared__ float xs[8][32];
  const int m0 = blockIdx.x*8, tid = threadIdx.x;
  xs[tid>>5][tid&31] = x[(size_t)(m0 + (tid>>5))*F_ + (tid&31)];
  __syncthreads();
  #pragma unroll
  for (int hf=0; hf<2; ++hf){
    const int e = tid + hf*256;
    float a[8];
    const float bb = bias[e];
    #pragma unroll
    for (int r=0;r<8;r++) a[r]=bb;
    for (int f=0; f<F_; ++f){
      const float wv = w[(size_t)f*D_ + e];
      #pragma unroll
      for (int r=0;r<8;r++) a[r] += xs[r][f]*wv;
    }
    #pragma unroll
    for (int r=0;r<8;r++) h[(size_t)(m0+r)*D_ + e] = a[r];
  }
}

// ---------------- LayerNorm over D=512 -> bf16 (one row / 128-thread block) ----------------
__global__ __launch_bounds__(128) void k_ln(const float* __restrict__ in, const float* __restrict__ w,
      u16* __restrict__ outb)
{
  const int row = blockIdx.x, tid = threadIdx.x;
  const f32x4* rp = (const f32x4*)(in + (size_t)row*D_);
  f32x4 v = rp[tid];
  float s = v[0]+v[1]+v[2]+v[3];
  float q = v[0]*v[0]+v[1]*v[1]+v[2]*v[2]+v[3]*v[3];
  #pragma unroll
  for (int off=32; off; off>>=1){ s += __shfl_down(s,off,64); q += __shfl_down(q,off,64); }
  __shared__ float red[2][2];
  if ((tid&63)==0){ red[tid>>6][0]=s; red[tid>>6][1]=q; }
  __syncthreads();
  const float sum = red[0][0]+red[1][0], sq = red[0][1]+red[1][1];
  const float mu  = sum*(1.f/D_);
  const float var = sq*(1.f/D_) - mu*mu;
  const float inv = rsqrtf(var + 1e-5f);
  f32x4 wv = ((const f32x4*)w)[tid];
  ushort4 ob;
  ob.x=f2bf((v[0]-mu)*inv*wv[0]); ob.y=f2bf((v[1]-mu)*inv*wv[1]);
  ob.z=f2bf((v[2]-mu)*inv*wv[2]); ob.w=f2bf((v[3]-mu)*inv*wv[3]);
  ((ushort4*)(outb + (size_t)row*D_))[tid] = ob;
}

// ---------------- causal depthwise conv (K=4) + SiLU -> bf16, s-chunked ----------------
// xnbf: full [b][s][D] bf16;  xcc: chunk [b][sl][D] bf16
__global__ void k_conv(const u16* __restrict__ xnbf, const float* __restrict__ cw,
                       const float* __restrict__ cb, u16* __restrict__ xcc,
                       int s0, int Sc)
{
  const int idx = blockIdx.x*256 + threadIdx.x;   // over B*Sc*128 quads
  const int e4 = idx & 127;
  const int sl = (idx >> 7) % Sc;
  const int b  = idx / (128*Sc);
  const int s  = s0 + sl;
  f32x4 acc = ((const f32x4*)cb)[e4];
  #pragma unroll
  for (int k=0;k<KK_;k++){
    const int sp = s - (KK_-1) + k;
    if (sp >= 0){
      f32x4 w4 = ((const f32x4*)cw)[k*128 + e4];
      ushort4 xq = ((const ushort4*)xnbf)[(size_t)(b*S_ + sp)*128 + e4];
      acc[0] += w4[0]*bf2f(xq.x);
      acc[1] += w4[1]*bf2f(xq.y);
      acc[2] += w4[2]*bf2f(xq.z);
      acc[3] += w4[3]*bf2f(xq.w);
    }
  }
  ushort4 o;
  float a;
  a=acc[0]; o.x=f2bf(a/(1.f+__expf(-a)));
  a=acc[1]; o.y=f2bf(a/(1.f+__expf(-a)));
  a=acc[2]; o.z=f2bf(a/(1.f+__expf(-a)));
  a=acc[3]; o.w=f2bf(a/(1.f+__expf(-a)));
  ((ushort4*)xcc)[idx] = o;
}

// ---------------- generic bf16 MFMA GEMM: C[M,N] (+)= A[M,K] @ B[K,N] ----------------
__global__ __launch_bounds__(256) void k_gemm_ffn(
    const u16* __restrict__ A, int lda,
    const u16* __restrict__ Bw, int ldb,
    float* __restrict__ C, int ldc,
    int Kdim, int addmode)
{
  __shared__ u16 As[128*40];
  __shared__ u16 Bs[128*40];
  const int tid = threadIdx.x;
  const int m0 = blockIdx.x * 128;
  const int n0 = blockIdx.y * 128;
  const int w = tid >> 6, l = tid & 63;
  const int l16 = l & 15, kg = l >> 4;
  f32x4 acc[2][8];
  #pragma unroll
  for (int i=0;i<2;i++)
    #pragma unroll
    for (int j=0;j<8;j++) acc[i][j] = (f32x4)0.f;
  const int nk = Kdim >> 5;
  for (int kt=0; kt<nk; ++kt){
    const int k0 = kt<<5;
    __syncthreads();
    #pragma unroll
    for (int p=0;p<2;p++){
      const int idx = p*256 + tid;
      const int row = idx>>2, kc = (idx&3)*8;
      s16x8 v = *(const s16x8*)(A + (size_t)(m0+row)*lda + k0 + kc);
      *(s16x8*)&As[row*40 + kc] = v;
    }
    {
      const int kp = tid>>4; const int nn = (tid&15)*8;
      const u16* bp = Bw + (size_t)(k0 + 2*kp)*ldb + n0 + nn;
      s16x8 r0 = *(const s16x8*)bp;
      s16x8 r1 = *(const s16x8*)(bp + ldb);
      #pragma unroll
      for (int j=0;j<8;j++){
        unsigned uu = (unsigned)(u16)r0[j] | ((unsigned)(u16)r1[j]<<16);
        *(unsigned*)&Bs[(nn+j)*40 + 2*kp] = uu;
      }
    }
    __syncthreads();
    s16x8 af[2];
    #pragma unroll
    for (int mf=0;mf<2;mf++)
      af[mf] = *(const s16x8*)&As[(w*32 + mf*16 + l16)*40 + kg*8];
    #pragma unroll
    for (int nf=0;nf<8;nf++){
      s16x8 bfr = *(const s16x8*)&Bs[(nf*16 + l16)*40 + kg*8];
      #pragma unroll
      for (int mf=0;mf<2;mf++)
        acc[mf][nf] = mfma16(af[mf], bfr, acc[mf][nf]);
    }
  }
  #pragma unroll
  for (int mf=0;mf<2;mf++){
    #pragma unroll
    for (int j=0;j<4;j++){
      const int row = m0 + w*32 + mf*16 + kg*4 + j;
      float* cp = C + (size_t)row*ldc + n0 + l16;
      #pragma unroll
      for (int nf=0;nf<8;nf++){
        const float v = acc[mf][nf][j];
        if (addmode) cp[nf*16] += v; else cp[nf*16] = v;
      }
    }
  }
}

// ---------------- gate projections (s-chunked) ----------------
// m in [0, B*Sc): b = m/Sc, sl = m%Sc
// g<2: A-row = xcc[m]  (chunk-local, contiguous)
// g>=2: A-row = xnbf[b*S + s0+sl]
// out: pre[(((g*Sc + sl)*B + b)*D) + hh*128+col] = acc + bias
__global__ __launch_bounds__(256) void k_gemm_gates(
    const u16* __restrict__ xcc, const u16* __restrict__ xnbf,
    const u16* __restrict__ wg,
    const float* __restrict__ bgates,
    float* __restrict__ pre, int s0, int Sc)
{
  __shared__ u16 As[128*40];
  __shared__ u16 Bs[128*40];
  const int tid = threadIdx.x;
  const int m0 = blockIdx.x * 128;
  const int gh = blockIdx.y; const int g = gh>>2, hh = gh&3;
  const u16* Bw = wg + (size_t)gh*DH_*DH_;
  const int w = tid >> 6, l = tid & 63;
  const int l16 = l & 15, kg = l >> 4;
  f32x4 acc[2][8];
  #pragma unroll
  for (int i=0;i<2;i++)
    #pragma unroll
    for (int j=0;j<8;j++) acc[i][j] = (f32x4)0.f;
  for (int kt=0; kt<4; ++kt){
    const int k0 = kt<<5;
    __syncthreads();
    #pragma unroll
    for (int p=0;p<2;p++){
      const int idx = p*256 + tid;
      const int row = idx>>2, kc = (idx&3)*8;
      const int m = m0 + row;
      size_t aoff;
      const u16* Abase;
      if (g < 2){ Abase = xcc;  aoff = (size_t)m*D_; }
      else {
        const int b2 = m / Sc, sl2 = m - b2*Sc;
        Abase = xnbf; aoff = (size_t)(b2*S_ + s0 + sl2)*D_;
      }
      s16x8 v = *(const s16x8*)(Abase + aoff + hh*DH_ + k0 + kc);
      *(s16x8*)&As[row*40 + kc] = v;
    }
    {
      const int kp = tid>>4; const int nn = (tid&15)*8;
      const u16* bp = Bw + (size_t)(k0 + 2*kp)*DH_ + nn;
      s16x8 r0 = *(const s16x8*)bp;
      s16x8 r1 = *(const s16x8*)(bp + DH_);
      #pragma unroll
      for (int j=0;j<8;j++){
        unsigned uu = (unsigned)(u16)r0[j] | ((unsigned)(u16)r1[j]<<16);
        *(unsigned*)&Bs[(nn+j)*40 + 2*kp] = uu;
      }
    }
    __syncthreads();
    s16x8 af[2];
    #pragma unroll
    for (int mf=0;mf<2;mf++)
      af[mf] = *(const s16x8*)&As[(w*32 + mf*16 + l16)*40 + kg*8];
    #pragma unroll
    for (int nf=0;nf<8;nf++){
      s16x8 bfr = *(const s16x8*)&Bs[(nf*16 + l16)*40 + kg*8];
      #pragma unroll
      for (int mf=0;mf<2;mf++)
        acc[mf][nf] = mfma16(af[mf], bfr, acc[mf][nf]);
    }
  }
  #pragma unroll
  for (int mf=0;mf<2;mf++){
    #pragma unroll
    for (int j=0;j<4;j++){
      const int m = m0 + w*32 + mf*16 + kg*4 + j;
      const int b2 = m / Sc;
      const int sl2 = m - b2*Sc;
      #pragma unroll
      for (int nf=0;nf<8;nf++){
        const int col = nf*16 + l16;
        const float bias = bgates[g*D_ + hh*128 + col];
        pre[(((size_t)g*Sc + sl2)*B_ + b2)*D_ + hh*128 + col] = acc[mf][nf][j] + bias;
      }
    }
  }
}

// ---------------- recurrent scan (s-chunked, state-carrying) ----------------
// one block = (head, 2 batches), 1024 threads; st: [4][B*NH*128] = h,c,n,m
__global__ __launch_bounds__(1024) void k_scan(
    const float* __restrict__ pre,
    const float* __restrict__ rg,
    const float* __restrict__ gnw,
    float* __restrict__ hG,
    float* __restrict__ st, int s0, int Sc)
{
  const int t  = threadIdx.x;
  const int hh = blockIdx.y;
  const int b0 = blockIdx.x * 2;
  const int g  = t >> 8;
  const int u  = t & 255;
  const int e  = u >> 1;
  const int dh = u & 1;

  __shared__ __align__(16) float hs[2][128];
  __shared__ float recl[4][2][128];
  __shared__ float red[2][2][2];

  float R_[64];
  {
    const float* rp = rg + ((size_t)(g*NH_ + hh)*128 + dh*64)*128 + e;
    #pragma unroll
    for (int i=0;i<64;i++) R_[i] = rp[(size_t)i*128];
  }

  const int bl = t >> 7;       // pointwise role (t<256)
  const int ep = t & 127;
  const int SCMP = B_*NH_*DH_; // 65536
  const int is  = ((b0+bl)*NH_ + hh)*128 + ep;
  float c=0.f, n=0.f, mst=0.f;
  float pc[4], pn[4];
  if (t < 256){
    hs[bl][ep] = st[0*SCMP + is];
    c   = st[1*SCMP + is];
    n   = st[2*SCMP + is];
    mst = st[3*SCMP + is];
    #pragma unroll
    for (int gg=0; gg<4; gg++)
      pc[gg] = pre[(((size_t)gg*Sc + 0)*B_ + (b0+bl))*D_ + hh*128 + ep];
  }
  const float gws = gnw[hh*128 + ep];
  __syncthreads();

  float hv = 0.f;
  for (int sl=0; sl<Sc; ++sl){
    // ---- matvec: rec[g][b][e] = sum_d hs[b][d] * R[g][h][d][e]
    float pa=0.f, pb=0.f;
    const float* h0 = &hs[0][dh*64];
    const float* h1 = &hs[1][dh*64];
    #pragma unroll
    for (int i=0;i<64;i+=4){
      f32x4 a4 = *(const f32x4*)(h0+i);
      f32x4 b4 = *(const f32x4*)(h1+i);
      pa += a4[0]*R_[i+0] + a4[1]*R_[i+1] + a4[2]*R_[i+2] + a4[3]*R_[i+3];
      pb += b4[0]*R_[i+0] + b4[1]*R_[i+1] + b4[2]*R_[i+2] + b4[3]*R_[i+3];
    }
    pa += __shfl_xor(pa, 1, 64);
    pb += __shfl_xor(pb, 1, 64);
    if (!dh){ recl[g][0][e] = pa; recl[g][1][e] = pb; }
    if (t < 256){
      const int sn = (sl+1 < Sc) ? sl+1 : sl;
      #pragma unroll
      for (int gg=0; gg<4; gg++)
        pn[gg] = pre[(((size_t)gg*Sc + sn)*B_ + (b0+bl))*D_ + hh*128 + ep];
    }
    __syncthreads();
    if (t < 256){
      const float iraw = pc[0] + recl[0][bl][ep];
      const float fraw = pc[1] + recl[1][bl][ep];
      const float zraw = pc[2] + recl[2][bl][ep];
      const float oraw = pc[3] + recl[3][bl][ep];
      const float lsig = fminf(fraw, 0.f) - log1pf(__expf(-fabsf(fraw)));
      const float lf   = mst + lsig;
      const float mn   = fmaxf(iraw, lf);
      const float ig   = __expf(iraw - mn);
      const float fg   = __expf(lf - mn);
      c = fg*c + ig*tanhf(zraw);
      n = fg*n + ig;
      const float sig_o = 1.f/(1.f + __expf(-oraw));
      hv = sig_o * c / n;
      mst = mn;
      hs[bl][ep] = hv;
      float sv = hv, sq = hv*hv;
      #pragma unroll
      for (int off=32; off; off>>=1){
        sv += __shfl_down(sv, off, 64);
        sq += __shfl_down(sq, off, 64);
      }
      if ((t&63)==0){ red[bl][(t>>6)&1][0]=sv; red[bl][(t>>6)&1][1]=sq; }
    }
    __syncthreads();
    if (t < 256){
      const float sum = red[bl][0][0] + red[bl][1][0];
      const float sq2 = red[bl][0][1] + red[bl][1][1];
      const float mu  = sum * (1.f/128.f);
      const float var = sq2 * (1.f/128.f) - mu*mu;
      const float y   = (hv - mu) * rsqrtf(var + 1e-5f) * gws;
      hG[(((size_t)(b0+bl)*S_) + (s0+sl))*D_ + hh*128 + ep] += y;
      pc[0]=pn[0]; pc[1]=pn[1]; pc[2]=pn[2]; pc[3]=pn[3];
    }
  }
  if (t < 256){
    st[0*SCMP + is] = hv;
    st[1*SCMP + is] = c;
    st[2*SCMP + is] = n;
    st[3*SCMP + is] = mst;
  }
}

// ---------------- GLU activation: act = gelu_tanh(gate) * up -> bf16 ----------------
__global__ void k_act(const float* __restrict__ u, u16* __restrict__ act){
  const int m = blockIdx.x;
  const float* up = u + (size_t)m*(2*UP_);
  u16* ap = act + (size_t)m*UP_;
  for (int j = threadIdx.x; j < UP_; j += 256){
    const float g = up[j], uv = up[j+UP_];
    const float t = tanhf(0.7978845608028654f*(g + 0.044715f*g*g*g));
    ap[j] = f2bf(0.5f*g*(1.f+t)*uv);
  }
}

// ---------------- final: post-LN(last token) -> fc1+relu -> fc2 ----------------
__global__ __launch_bounds__(256) void k_head(const float* __restrict__ h,
     const float* __restrict__ pw, const float* __restrict__ f1w, const float* __restrict__ f1b,
     const float* __restrict__ f2w, const float* __restrict__ f2bias, float* __restrict__ out)
{
  const int b = blockIdx.x, tid = threadIdx.x;
  __shared__ float nrm[512];
  __shared__ float a1[256];
  __shared__ float red[4][2];
  const float* row = h + ((size_t)b*S_ + (S_-1))*D_;
  const float v0 = row[tid], v1 = row[tid+256];
  float s = v0+v1, q = v0*v0+v1*v1;
  #pragma unroll
  for (int off=32; off; off>>=1){ s += __shfl_down(s,off,64); q += __shfl_down(q,off,64); }
  if ((tid&63)==0){ red[tid>>6][0]=s; red[tid>>6][1]=q; }
  __syncthreads();
  const float sum = red[0][0]+red[1][0]+red[2][0]+red[3][0];
  const float sq  = red[0][1]+red[1][1]+red[2][1]+red[3][1];
  const float mu  = sum*(1.f/D_), var = sq*(1.f/D_) - mu*mu;
  const float inv = rsqrtf(var+1e-5f);
  nrm[tid]      = (v0-mu)*inv*pw[tid];
  nrm[tid+256]  = (v1-mu)*inv*pw[tid+256];
  __syncthreads();
  float acc = f1b[tid];
  for (int d=0; d<D_; ++d) acc += nrm[d]*f1w[(size_t)d*256 + tid];
  a1[tid] = fmaxf(acc, 0.f);
  __syncthreads();
  if (tid < FD_){
    float o = f2bias[tid];
    for (int i=0;i<256;++i) o += a1[i]*f2w[(size_t)i*FD_ + tid];
    out[b*FD_ + tid] = o;
  }
}

// ---------------- launcher ----------------
extern "C" void kernel_launch(void* const* d_in, const int* in_sizes, int n_in,
                              void* d_out, int out_size, void* d_ws, size_t ws_size,
                              hipStream_t stream)
{
  const float* x       = (const float*)d_in[0];
  const float* w_in    = (const float*)d_in[1];
  const float* b_in    = (const float*)d_in[2];
  const float* ln1_w   = (const float*)d_in[3];
  const float* conv_w  = (const float*)d_in[4];
  const float* conv_b  = (const float*)d_in[5];
  const float* w_gates = (const float*)d_in[6];
  const float* r_gates = (const float*)d_in[7];
  const float* b_gates = (const float*)d_in[8];
  const float* gn_w    = (const float*)d_in[9];
  const float* ln2_w   = (const float*)d_in[10];
  const float* ff_up   = (const float*)d_in[11];
  const float* ff_down = (const float*)d_in[12];
  const float* post_ln = (const float*)d_in[13];
  const float* fc1_w   = (const float*)d_in[14];
  const float* fc1_b   = (const float*)d_in[15];
  const float* fc2_w   = (const float*)d_in[16];
  const float* fc2_b   = (const float*)d_in[17];
  float* out = (float*)d_out;

  // ---- persistent workspace layout (bytes, all 256-aligned) ----
  char* ws = (char*)d_ws;
  const size_t OFF_H     = 0;          // f32 h           52,428,800
  const size_t OFF_XNBF  = 52428800;   // bf16 xn/xn2     26,214,400
  const size_t OFF_WGBF  = 78643200;   // bf16 w_gates     1,048,576
  const size_t OFF_UPBF  = 79691776;   // bf16 ff_up       2,883,584
  const size_t OFF_DNBF  = 82575360;   // bf16 ff_down     1,441,792
  const size_t OFF_STATE = 84017152;   // f32 scan state   1,048,576
  const size_t OFF_CHUNK = 85065728;   // chunked region (rest)

  if (ws_size < OFF_CHUNK + 1179648ull){
    k_sentinel<<<4, 256, 0, stream>>>(out, out_size);   // unambiguous "ws too small"
    return;
  }
  const size_t CR = ws_size - OFF_CHUNK;
  // per-s cost: pre f32 (4*B*D*4 = 1,048,576) + xc bf16 (B*D*2 = 131,072)
  int Sc = (int)(CR / 1179648ull); if (Sc > S_) Sc = S_;
  // per-M-row cost: u f32 (2*UP*4 = 5632) + act bf16 (UP*2 = 1408)
  int Mc = (int)((CR / 7040ull) & ~(size_t)127); if (Mc > M_) Mc = M_;

  float* h     = (float*)(ws + OFF_H);
  u16*   xnbf  = (u16*)  (ws + OFF_XNBF);
  u16*   wgbf  = (u16*)  (ws + OFF_WGBF);
  u16*   upbf  = (u16*)  (ws + OFF_UPBF);
  u16*   dnbf  = (u16*)  (ws + OFF_DNBF);
  float* st    = (float*)(ws + OFF_STATE);
  u16*   xcc   = (u16*)  (ws + OFF_CHUNK);
  float* prec  = (float*)(ws + OFF_CHUNK + (size_t)Sc*131072);
  float* uc    = (float*)(ws + OFF_CHUNK);
  u16*   actc  = (u16*)  (ws + OFF_CHUNK + (size_t)Mc*5632);

  // cast weights to bf16 (all blocks at once)
  {
    int n1 = NB_*4*NH_*DH_*DH_;  k_cast<<<(n1+255)/256, 256, 0, stream>>>(w_gates, wgbf, n1);
    int n2 = NB_*D_*2*UP_;       k_cast<<<(n2+255)/256, 256, 0, stream>>>(ff_up,   upbf, n2);
    int n3 = NB_*UP_*D_;         k_cast<<<(n3+255)/256, 256, 0, stream>>>(ff_down, dnbf, n3);
  }

  k_inproj<<<M_/8, 256, 0, stream>>>(x, w_in, b_in, h);

  for (int blk=0; blk<NB_; ++blk){
    // LN1 -> bf16
    k_ln<<<M_, 128, 0, stream>>>(h, ln1_w + blk*D_, xnbf);
    // zero scan state
    k_zero<<<1024, 256, 0, stream>>>(st, 4*B_*NH_*DH_);
    // s-chunked: conv -> gate GEMMs -> scan
    for (int s0=0; s0<S_; s0+=Sc){
      const int scur = (S_ - s0 < Sc) ? (S_ - s0) : Sc;
      k_conv<<<scur*64, 256, 0, stream>>>(xnbf, conv_w + blk*KK_*D_, conv_b + blk*D_,
                                          xcc, s0, scur);
      dim3 gg(scur, 16);
      k_gemm_gates<<<gg, 256, 0, stream>>>(xcc, xnbf,
          wgbf + (size_t)blk*4*NH_*DH_*DH_, b_gates + (size_t)blk*4*D_, prec, s0, scur);
      dim3 gs(B_/2, NH_);
      k_scan<<<gs, 1024, 0, stream>>>(prec, r_gates + (size_t)blk*4*NH_*DH_*DH_,
                                      gn_w + blk*D_, h, st, s0, scur);
    }
    // LN2 -> bf16
    k_ln<<<M_, 128, 0, stream>>>(h, ln2_w + blk*D_, xnbf);
    // M-chunked FFN
    for (int m0c=0; m0c<M_; m0c+=Mc){
      const int mcur = (M_ - m0c < Mc) ? (M_ - m0c) : Mc;
      dim3 g1(mcur/128, (2*UP_)/128);   // 11 n-blocks
      k_gemm_ffn<<<g1, 256, 0, stream>>>(xnbf + (size_t)m0c*D_, D_,
                                         upbf + (size_t)blk*D_*2*UP_, 2*UP_,
                                         uc, 2*UP_, D_, 0);
      k_act<<<mcur, 256, 0, stream>>>(uc, actc);
      dim3 g2(mcur/128, D_/128);        // 4 n-blocks
      k_gemm_ffn<<<g2, 256, 0, stream>>>(actc, UP_,
                                         dnbf + (size_t)blk*UP_*D_, D_,
                                         h + (size_t)m0c*D_, D_, UP_, 1);
    }
  }

  k_head<<<B_, 256, 0, stream>>>(h, post_ln, fc1_w, fc1_b, fc2_w, fc2_b, out);
}

// Round 3
// 1494.680 us; speedup vs baseline: 1.2657x; 1.2657x over previous
//
#include <hip/hip_runtime.h>

// ---------------- problem constants ----------------
#define B_  128
#define S_  200
#define F_  32
#define D_  512
#define NH_ 4
#define DH_ 128
#define KK_ 4
#define NB_ 2
#define UP_ 704
#define FD_ 7
#define M_  (B_*S_)   // 25600 rows

typedef unsigned short u16;
typedef _Float16 f16;
typedef __attribute__((ext_vector_type(2))) _Float16 f16x2;
typedef __attribute__((ext_vector_type(8))) short  s16x8;
typedef __attribute__((ext_vector_type(4))) float  f32x4;

__device__ __forceinline__ u16 f2bf(float f){
  unsigned x = __builtin_bit_cast(unsigned, f);
  return (u16)((x + 0x7fffu + ((x>>16)&1u)) >> 16);   // RNE
}
__device__ __forceinline__ float bf2f(u16 u){
  return __builtin_bit_cast(float, (unsigned)u << 16);
}
__device__ __forceinline__ f32x4 mfma16(s16x8 a, s16x8 b, f32x4 c){
  return __builtin_amdgcn_mfma_f32_16x16x32_bf16(a, b, c, 0, 0, 0);
}

// ---------------- tiny utility kernels ----------------
__global__ void k_cast(const float* __restrict__ in, u16* __restrict__ out, int n){
  int i = blockIdx.x*256 + threadIdx.x;
  if (i < n) out[i] = f2bf(in[i]);
}
__global__ void k_zero(float* __restrict__ p, int n){
  int i = blockIdx.x*256 + threadIdx.x;
  if (i < n) p[i] = 0.f;
}
__global__ void k_sentinel(float* __restrict__ out, int n){
  int i = blockIdx.x*256 + threadIdx.x;
  if (i < n) out[i] = -12345.0f;
}

// ---------------- input projection: h = x @ w_in + b_in ----------------
__global__ __launch_bounds__(256) void k_inproj(const float* __restrict__ x,
    const float* __restrict__ w, const float* __restrict__ bias, float* __restrict__ h)
{
  __shared__ float xs[8][32];
  const int m0 = blockIdx.x*8, tid = threadIdx.x;
  xs[tid>>5][tid&31] = x[(size_t)(m0 + (tid>>5))*F_ + (tid&31)];
  __syncthreads();
  #pragma unroll
  for (int hf=0; hf<2; ++hf){
    const int e = tid + hf*256;
    float a[8];
    const float bb = bias[e];
    #pragma unroll
    for (int r=0;r<8;r++) a[r]=bb;
    for (int f=0; f<F_; ++f){
      const float wv = w[(size_t)f*D_ + e];
      #pragma unroll
      for (int r=0;r<8;r++) a[r] += xs[r][f]*wv;
    }
    #pragma unroll
    for (int r=0;r<8;r++) h[(size_t)(m0+r)*D_ + e] = a[r];
  }
}

// ---------------- LayerNorm over D=512 -> bf16 (one row / 128-thread block) ----------------
__global__ __launch_bounds__(128) void k_ln(const float* __restrict__ in, const float* __restrict__ w,
      u16* __restrict__ outb)
{
  const int row = blockIdx.x, tid = threadIdx.x;
  const f32x4* rp = (const f32x4*)(in + (size_t)row*D_);
  f32x4 v = rp[tid];
  float s = v[0]+v[1]+v[2]+v[3];
  float q = v[0]*v[0]+v[1]*v[1]+v[2]*v[2]+v[3]*v[3];
  #pragma unroll
  for (int off=32; off; off>>=1){ s += __shfl_down(s,off,64); q += __shfl_down(q,off,64); }
  __shared__ float red[2][2];
  if ((tid&63)==0){ red[tid>>6][0]=s; red[tid>>6][1]=q; }
  __syncthreads();
  const float sum = red[0][0]+red[1][0], sq = red[0][1]+red[1][1];
  const float mu  = sum*(1.f/D_);
  const float var = sq*(1.f/D_) - mu*mu;
  const float inv = rsqrtf(var + 1e-5f);
  f32x4 wv = ((const f32x4*)w)[tid];
  ushort4 ob;
  ob.x=f2bf((v[0]-mu)*inv*wv[0]); ob.y=f2bf((v[1]-mu)*inv*wv[1]);
  ob.z=f2bf((v[2]-mu)*inv*wv[2]); ob.w=f2bf((v[3]-mu)*inv*wv[3]);
  ((ushort4*)(outb + (size_t)row*D_))[tid] = ob;
}

// ---------------- causal depthwise conv (K=4) + SiLU -> bf16, s-chunked ----------------
__global__ void k_conv(const u16* __restrict__ xnbf, const float* __restrict__ cw,
                       const float* __restrict__ cb, u16* __restrict__ xcc,
                       int s0, int Sc)
{
  const int idx = blockIdx.x*256 + threadIdx.x;   // over B*Sc*128 quads
  const int e4 = idx & 127;
  const int sl = (idx >> 7) % Sc;
  const int b  = idx / (128*Sc);
  const int s  = s0 + sl;
  f32x4 acc = ((const f32x4*)cb)[e4];
  #pragma unroll
  for (int k=0;k<KK_;k++){
    const int sp = s - (KK_-1) + k;
    if (sp >= 0){
      f32x4 w4 = ((const f32x4*)cw)[k*128 + e4];
      ushort4 xq = ((const ushort4*)xnbf)[(size_t)(b*S_ + sp)*128 + e4];
      acc[0] += w4[0]*bf2f(xq.x);
      acc[1] += w4[1]*bf2f(xq.y);
      acc[2] += w4[2]*bf2f(xq.z);
      acc[3] += w4[3]*bf2f(xq.w);
    }
  }
  ushort4 o;
  float a;
  a=acc[0]; o.x=f2bf(a/(1.f+__expf(-a)));
  a=acc[1]; o.y=f2bf(a/(1.f+__expf(-a)));
  a=acc[2]; o.z=f2bf(a/(1.f+__expf(-a)));
  a=acc[3]; o.w=f2bf(a/(1.f+__expf(-a)));
  ((ushort4*)xcc)[idx] = o;
}

// ---------------- generic bf16 MFMA GEMM: C[M,N] (+)= A[M,K] @ B[K,N] ----------------
__global__ __launch_bounds__(256) void k_gemm_ffn(
    const u16* __restrict__ A, int lda,
    const u16* __restrict__ Bw, int ldb,
    float* __restrict__ C, int ldc,
    int Kdim, int addmode)
{
  __shared__ u16 As[128*40];
  __shared__ u16 Bs[128*40];
  const int tid = threadIdx.x;
  const int m0 = blockIdx.x * 128;
  const int n0 = blockIdx.y * 128;
  const int w = tid >> 6, l = tid & 63;
  const int l16 = l & 15, kg = l >> 4;
  f32x4 acc[2][8];
  #pragma unroll
  for (int i=0;i<2;i++)
    #pragma unroll
    for (int j=0;j<8;j++) acc[i][j] = (f32x4)0.f;
  const int nk = Kdim >> 5;
  for (int kt=0; kt<nk; ++kt){
    const int k0 = kt<<5;
    __syncthreads();
    #pragma unroll
    for (int p=0;p<2;p++){
      const int idx = p*256 + tid;
      const int row = idx>>2, kc = (idx&3)*8;
      s16x8 v = *(const s16x8*)(A + (size_t)(m0+row)*lda + k0 + kc);
      *(s16x8*)&As[row*40 + kc] = v;
    }
    {
      const int kp = tid>>4; const int nn = (tid&15)*8;
      const u16* bp = Bw + (size_t)(k0 + 2*kp)*ldb + n0 + nn;
      s16x8 r0 = *(const s16x8*)bp;
      s16x8 r1 = *(const s16x8*)(bp + ldb);
      #pragma unroll
      for (int j=0;j<8;j++){
        unsigned uu = (unsigned)(u16)r0[j] | ((unsigned)(u16)r1[j]<<16);
        *(unsigned*)&Bs[(nn+j)*40 + 2*kp] = uu;
      }
    }
    __syncthreads();
    s16x8 af[2];
    #pragma unroll
    for (int mf=0;mf<2;mf++)
      af[mf] = *(const s16x8*)&As[(w*32 + mf*16 + l16)*40 + kg*8];
    #pragma unroll
    for (int nf=0;nf<8;nf++){
      s16x8 bfr = *(const s16x8*)&Bs[(nf*16 + l16)*40 + kg*8];
      #pragma unroll
      for (int mf=0;mf<2;mf++)
        acc[mf][nf] = mfma16(af[mf], bfr, acc[mf][nf]);
    }
  }
  #pragma unroll
  for (int mf=0;mf<2;mf++){
    #pragma unroll
    for (int j=0;j<4;j++){
      const int row = m0 + w*32 + mf*16 + kg*4 + j;
      float* cp = C + (size_t)row*ldc + n0 + l16;
      #pragma unroll
      for (int nf=0;nf<8;nf++){
        const float v = acc[mf][nf][j];
        if (addmode) cp[nf*16] += v; else cp[nf*16] = v;
      }
    }
  }
}

// ---------------- gate projections (s-chunked) ----------------
__global__ __launch_bounds__(256) void k_gemm_gates(
    const u16* __restrict__ xcc, const u16* __restrict__ xnbf,
    const u16* __restrict__ wg,
    const float* __restrict__ bgates,
    float* __restrict__ pre, int s0, int Sc)
{
  __shared__ u16 As[128*40];
  __shared__ u16 Bs[128*40];
  const int tid = threadIdx.x;
  const int m0 = blockIdx.x * 128;
  const int gh = blockIdx.y; const int g = gh>>2, hh = gh&3;
  const u16* Bw = wg + (size_t)gh*DH_*DH_;
  const int w = tid >> 6, l = tid & 63;
  const int l16 = l & 15, kg = l >> 4;
  f32x4 acc[2][8];
  #pragma unroll
  for (int i=0;i<2;i++)
    #pragma unroll
    for (int j=0;j<8;j++) acc[i][j] = (f32x4)0.f;
  for (int kt=0; kt<4; ++kt){
    const int k0 = kt<<5;
    __syncthreads();
    #pragma unroll
    for (int p=0;p<2;p++){
      const int idx = p*256 + tid;
      const int row = idx>>2, kc = (idx&3)*8;
      const int m = m0 + row;
      size_t aoff;
      const u16* Abase;
      if (g < 2){ Abase = xcc;  aoff = (size_t)m*D_; }
      else {
        const int b2 = m / Sc, sl2 = m - b2*Sc;
        Abase = xnbf; aoff = (size_t)(b2*S_ + s0 + sl2)*D_;
      }
      s16x8 v = *(const s16x8*)(Abase + aoff + hh*DH_ + k0 + kc);
      *(s16x8*)&As[row*40 + kc] = v;
    }
    {
      const int kp = tid>>4; const int nn = (tid&15)*8;
      const u16* bp = Bw + (size_t)(k0 + 2*kp)*DH_ + nn;
      s16x8 r0 = *(const s16x8*)bp;
      s16x8 r1 = *(const s16x8*)(bp + DH_);
      #pragma unroll
      for (int j=0;j<8;j++){
        unsigned uu = (unsigned)(u16)r0[j] | ((unsigned)(u16)r1[j]<<16);
        *(unsigned*)&Bs[(nn+j)*40 + 2*kp] = uu;
      }
    }
    __syncthreads();
    s16x8 af[2];
    #pragma unroll
    for (int mf=0;mf<2;mf++)
      af[mf] = *(const s16x8*)&As[(w*32 + mf*16 + l16)*40 + kg*8];
    #pragma unroll
    for (int nf=0;nf<8;nf++){
      s16x8 bfr = *(const s16x8*)&Bs[(nf*16 + l16)*40 + kg*8];
      #pragma unroll
      for (int mf=0;mf<2;mf++)
        acc[mf][nf] = mfma16(af[mf], bfr, acc[mf][nf]);
    }
  }
  #pragma unroll
  for (int mf=0;mf<2;mf++){
    #pragma unroll
    for (int j=0;j<4;j++){
      const int m = m0 + w*32 + mf*16 + kg*4 + j;
      const int b2 = m / Sc;
      const int sl2 = m - b2*Sc;
      #pragma unroll
      for (int nf=0;nf<8;nf++){
        const int col = nf*16 + l16;
        const float bias = bgates[g*D_ + hh*128 + col];
        pre[(((size_t)g*Sc + sl2)*B_ + b2)*D_ + hh*128 + col] = acc[mf][nf][j] + bias;
      }
    }
  }
}

// ---------------- recurrent scan (s-chunked, state-carrying) ----------------
// one block = (head, 2 batches), 512 threads = (gate g: 4) x (column e: 128).
// R held as 64 packed f16 pairs in VGPRs; h broadcast via v_readlane + v_dot2_f32_f16.
__global__ __launch_bounds__(512) void k_scan(
    const float* __restrict__ pre,
    const float* __restrict__ rg,
    const float* __restrict__ gnw,
    float* __restrict__ hG,
    float* __restrict__ st, int s0, int Sc)
{
  const int t  = threadIdx.x;
  const int hh = blockIdx.y;
  const int b0 = blockIdx.x * 2;
  const int g  = t >> 7;        // gate 0..3
  const int e  = t & 127;       // output column
  const int l  = t & 63;        // lane in wave

  __shared__ f16   hs16[2][128];
  __shared__ float recl[4][2][128];
  __shared__ float red[2][2][2];

  // R2[i] = (R[g][hh][2i][e], R[g][hh][2i+1][e]) as f16 pair
  f16x2 R2[64];
  {
    const float* rp = rg + ((size_t)(g*NH_ + hh)*DH_)*DH_ + e;
    #pragma unroll
    for (int i=0;i<64;i++){
      f16x2 p;
      p.x = (f16)rp[(size_t)(2*i)*DH_];
      p.y = (f16)rp[(size_t)(2*i+1)*DH_];
      R2[i] = p;
    }
  }

  const int bl = g & 1;         // pointwise role (t<256): batch-lane 0/1
  const int ep = e;
  const int SCMP = B_*NH_*DH_;  // 65536
  const int is  = ((b0+bl)*NH_ + hh)*128 + ep;
  float c=0.f, n=0.f, mst=0.f;
  float pc[4], pn[4];
  if (t < 256){
    const float h0 = st[0*SCMP + is];
    hs16[bl][ep] = (f16)h0;
    c   = st[1*SCMP + is];
    n   = st[2*SCMP + is];
    mst = st[3*SCMP + is];
    #pragma unroll
    for (int gg=0; gg<4; gg++)
      pc[gg] = pre[(((size_t)gg*Sc + 0)*B_ + (b0+bl))*D_ + hh*128 + ep];
  }
  const float gws = gnw[hh*128 + ep];
  __syncthreads();

  float hv = 0.f;
  for (int sl=0; sl<Sc; ++sl){
    // ---- matvec: rec[g][b][e] = sum_d h[b][d] * R[g][hh][d][e]  (f16 dot2, f32 accum)
    int vh0 = *(const int*)&hs16[0][2*l];
    int vh1 = *(const int*)&hs16[1][2*l];
    float acc0 = 0.f, acc1 = 0.f;
    #pragma unroll
    for (int i=0;i<64;i++){
      const int p0 = __builtin_amdgcn_readlane(vh0, i);
      const int p1 = __builtin_amdgcn_readlane(vh1, i);
      acc0 = __builtin_amdgcn_fdot2(R2[i], __builtin_bit_cast(f16x2, p0), acc0, false);
      acc1 = __builtin_amdgcn_fdot2(R2[i], __builtin_bit_cast(f16x2, p1), acc1, false);
    }
    recl[g][0][e] = acc0;
    recl[g][1][e] = acc1;
    // prefetch next step's gate pre-activations (global)
    if (t < 256){
      const int sn = (sl+1 < Sc) ? sl+1 : sl;
      #pragma unroll
      for (int gg=0; gg<4; gg++)
        pn[gg] = pre[(((size_t)gg*Sc + sn)*B_ + (b0+bl))*D_ + hh*128 + ep];
    }
    __syncthreads();
    if (t < 256){
      const float iraw = pc[0] + recl[0][bl][ep];
      const float fraw = pc[1] + recl[1][bl][ep];
      const float zraw = pc[2] + recl[2][bl][ep];
      const float oraw = pc[3] + recl[3][bl][ep];
      const float lsig = fminf(fraw, 0.f) - log1pf(__expf(-fabsf(fraw)));
      const float lf   = mst + lsig;
      const float mn   = fmaxf(iraw, lf);
      const float ig   = __expf(iraw - mn);
      const float fg   = __expf(lf - mn);
      c = fg*c + ig*tanhf(zraw);
      n = fg*n + ig;
      const float sig_o = 1.f/(1.f + __expf(-oraw));
      hv = sig_o * c / n;
      mst = mn;
      hs16[bl][ep] = (f16)hv;
      float sv = hv, sq = hv*hv;
      #pragma unroll
      for (int off=32; off; off>>=1){
        sv += __shfl_down(sv, off, 64);
        sq += __shfl_down(sq, off, 64);
      }
      if ((t&63)==0){ red[bl][(t>>6)&1][0]=sv; red[bl][(t>>6)&1][1]=sq; }
    }
    __syncthreads();
    if (t < 256){
      const float sum = red[bl][0][0] + red[bl][1][0];
      const float sq2 = red[bl][0][1] + red[bl][1][1];
      const float mu  = sum * (1.f/128.f);
      const float var = sq2 * (1.f/128.f) - mu*mu;
      const float y   = (hv - mu) * rsqrtf(var + 1e-5f) * gws;
      hG[(((size_t)(b0+bl)*S_) + (s0+sl))*D_ + hh*128 + ep] += y;
      pc[0]=pn[0]; pc[1]=pn[1]; pc[2]=pn[2]; pc[3]=pn[3];
    }
  }
  if (t < 256){
    st[0*SCMP + is] = hv;
    st[1*SCMP + is] = c;
    st[2*SCMP + is] = n;
    st[3*SCMP + is] = mst;
  }
}

// ---------------- GLU activation: act = gelu_tanh(gate) * up -> bf16 ----------------
__global__ void k_act(const float* __restrict__ u, u16* __restrict__ act){
  const int m = blockIdx.x;
  const float* up = u + (size_t)m*(2*UP_);
  u16* ap = act + (size_t)m*UP_;
  for (int j = threadIdx.x; j < UP_; j += 256){
    const float g = up[j], uv = up[j+UP_];
    const float t = tanhf(0.7978845608028654f*(g + 0.044715f*g*g*g));
    ap[j] = f2bf(0.5f*g*(1.f+t)*uv);
  }
}

// ---------------- final: post-LN(last token) -> fc1+relu -> fc2 ----------------
__global__ __launch_bounds__(256) void k_head(const float* __restrict__ h,
     const float* __restrict__ pw, const float* __restrict__ f1w, const float* __restrict__ f1b,
     const float* __restrict__ f2w, const float* __restrict__ f2bias, float* __restrict__ out)
{
  const int b = blockIdx.x, tid = threadIdx.x;
  __shared__ float nrm[512];
  __shared__ float a1[256];
  __shared__ float red[4][2];
  const float* row = h + ((size_t)b*S_ + (S_-1))*D_;
  const float v0 = row[tid], v1 = row[tid+256];
  float s = v0+v1, q = v0*v0+v1*v1;
  #pragma unroll
  for (int off=32; off; off>>=1){ s += __shfl_down(s,off,64); q += __shfl_down(q,off,64); }
  if ((tid&63)==0){ red[tid>>6][0]=s; red[tid>>6][1]=q; }
  __syncthreads();
  const float sum = red[0][0]+red[1][0]+red[2][0]+red[3][0];
  const float sq  = red[0][1]+red[1][1]+red[2][1]+red[3][1];
  const float mu  = sum*(1.f/D_), var = sq*(1.f/D_) - mu*mu;
  const float inv = rsqrtf(var+1e-5f);
  nrm[tid]      = (v0-mu)*inv*pw[tid];
  nrm[tid+256]  = (v1-mu)*inv*pw[tid+256];
  __syncthreads();
  float acc = f1b[tid];
  for (int d=0; d<D_; ++d) acc += nrm[d]*f1w[(size_t)d*256 + tid];
  a1[tid] = fmaxf(acc, 0.f);
  __syncthreads();
  if (tid < FD_){
    float o = f2bias[tid];
    for (int i=0;i<256;++i) o += a1[i]*f2w[(size_t)i*FD_ + tid];
    out[b*FD_ + tid] = o;
  }
}

// ---------------- launcher ----------------
extern "C" void kernel_launch(void* const* d_in, const int* in_sizes, int n_in,
                              void* d_out, int out_size, void* d_ws, size_t ws_size,
                              hipStream_t stream)
{
  const float* x       = (const float*)d_in[0];
  const float* w_in    = (const float*)d_in[1];
  const float* b_in    = (const float*)d_in[2];
  const float* ln1_w   = (const float*)d_in[3];
  const float* conv_w  = (const float*)d_in[4];
  const float* conv_b  = (const float*)d_in[5];
  const float* w_gates = (const float*)d_in[6];
  const float* r_gates = (const float*)d_in[7];
  const float* b_gates = (const float*)d_in[8];
  const float* gn_w    = (const float*)d_in[9];
  const float* ln2_w   = (const float*)d_in[10];
  const float* ff_up   = (const float*)d_in[11];
  const float* ff_down = (const float*)d_in[12];
  const float* post_ln = (const float*)d_in[13];
  const float* fc1_w   = (const float*)d_in[14];
  const float* fc1_b   = (const float*)d_in[15];
  const float* fc2_w   = (const float*)d_in[16];
  const float* fc2_b   = (const float*)d_in[17];
  float* out = (float*)d_out;

  // ---- persistent workspace layout (bytes, all 256-aligned) ----
  char* ws = (char*)d_ws;
  const size_t OFF_H     = 0;          // f32 h           52,428,800
  const size_t OFF_XNBF  = 52428800;   // bf16 xn/xn2     26,214,400
  const size_t OFF_WGBF  = 78643200;   // bf16 w_gates     1,048,576
  const size_t OFF_UPBF  = 79691776;   // bf16 ff_up       2,883,584
  const size_t OFF_DNBF  = 82575360;   // bf16 ff_down     1,441,792
  const size_t OFF_STATE = 84017152;   // f32 scan state   1,048,576
  const size_t OFF_CHUNK = 85065728;   // chunked region (rest)

  if (ws_size < OFF_CHUNK + 1179648ull){
    k_sentinel<<<4, 256, 0, stream>>>(out, out_size);   // unambiguous "ws too small"
    return;
  }
  const size_t CR = ws_size - OFF_CHUNK;
  // per-s cost: pre f32 (4*B*D*4 = 1,048,576) + xc bf16 (B*D*2 = 131,072)
  int Sc = (int)(CR / 1179648ull); if (Sc > S_) Sc = S_;
  // per-M-row cost: u f32 (2*UP*4 = 5632) + act bf16 (UP*2 = 1408)
  int Mc = (int)((CR / 7040ull) & ~(size_t)127); if (Mc > M_) Mc = M_;

  float* h     = (float*)(ws + OFF_H);
  u16*   xnbf  = (u16*)  (ws + OFF_XNBF);
  u16*   wgbf  = (u16*)  (ws + OFF_WGBF);
  u16*   upbf  = (u16*)  (ws + OFF_UPBF);
  u16*   dnbf  = (u16*)  (ws + OFF_DNBF);
  float* st    = (float*)(ws + OFF_STATE);
  u16*   xcc   = (u16*)  (ws + OFF_CHUNK);
  float* prec  = (float*)(ws + OFF_CHUNK + (size_t)Sc*131072);
  float* uc    = (float*)(ws + OFF_CHUNK);
  u16*   actc  = (u16*)  (ws + OFF_CHUNK + (size_t)Mc*5632);

  // cast weights to bf16 (all blocks at once)
  {
    int n1 = NB_*4*NH_*DH_*DH_;  k_cast<<<(n1+255)/256, 256, 0, stream>>>(w_gates, wgbf, n1);
    int n2 = NB_*D_*2*UP_;       k_cast<<<(n2+255)/256, 256, 0, stream>>>(ff_up,   upbf, n2);
    int n3 = NB_*UP_*D_;         k_cast<<<(n3+255)/256, 256, 0, stream>>>(ff_down, dnbf, n3);
  }

  k_inproj<<<M_/8, 256, 0, stream>>>(x, w_in, b_in, h);

  for (int blk=0; blk<NB_; ++blk){
    // LN1 -> bf16
    k_ln<<<M_, 128, 0, stream>>>(h, ln1_w + blk*D_, xnbf);
    // zero scan state
    k_zero<<<1024, 256, 0, stream>>>(st, 4*B_*NH_*DH_);
    // s-chunked: conv -> gate GEMMs -> scan
    for (int s0=0; s0<S_; s0+=Sc){
      const int scur = (S_ - s0 < Sc) ? (S_ - s0) : Sc;
      k_conv<<<scur*64, 256, 0, stream>>>(xnbf, conv_w + blk*KK_*D_, conv_b + blk*D_,
                                          xcc, s0, scur);
      dim3 gg(scur, 16);
      k_gemm_gates<<<gg, 256, 0, stream>>>(xcc, xnbf,
          wgbf + (size_t)blk*4*NH_*DH_*DH_, b_gates + (size_t)blk*4*D_, prec, s0, scur);
      dim3 gs(B_/2, NH_);
      k_scan<<<gs, 512, 0, stream>>>(prec, r_gates + (size_t)blk*4*NH_*DH_*DH_,
                                     gn_w + blk*D_, h, st, s0, scur);
    }
    // LN2 -> bf16
    k_ln<<<M_, 128, 0, stream>>>(h, ln2_w + blk*D_, xnbf);
    // M-chunked FFN
    for (int m0c=0; m0c<M_; m0c+=Mc){
      const int mcur = (M_ - m0c < Mc) ? (M_ - m0c) : Mc;
      dim3 g1(mcur/128, (2*UP_)/128);   // 11 n-blocks
      k_gemm_ffn<<<g1, 256, 0, stream>>>(xnbf + (size_t)m0c*D_, D_,
                                         upbf + (size_t)blk*D_*2*UP_, 2*UP_,
                                         uc, 2*UP_, D_, 0);
      k_act<<<mcur, 256, 0, stream>>>(uc, actc);
      dim3 g2(mcur/128, D_/128);        // 4 n-blocks
      k_gemm_ffn<<<g2, 256, 0, stream>>>(actc, UP_,
                                         dnbf + (size_t)blk*UP_*D_, D_,
                                         h + (size_t)m0c*D_, D_, UP_, 1);
    }
  }

  k_head<<<B_, 256, 0, stream>>>(h, post_ln, fc1_w, fc1_b, fc2_w, fc2_b, out);
}